// Round 6
// baseline (190.387 us; speedup 1.0000x reference)
//
#include <hip/hip_runtime.h>
#include <hip/hip_bf16.h>

// CausalAttention MI355X: B=2 L=2048 D=1024 H=16 HD=64
// convert -> QKV GEMM (256x256 ring-4 deep pipeline, counted vmcnt) ->
// flash attention (LDS K/V, swapped-operand) -> out GEMM (same ring kernel).

using bf16x8 = __attribute__((ext_vector_type(8))) short;
using f32x4  = __attribute__((ext_vector_type(4))) float;

static __device__ __forceinline__ unsigned short f2b(float f) {
  unsigned u = __builtin_bit_cast(unsigned, f);
  unsigned r = (u + 0x7fffu + ((u >> 16) & 1u)) >> 16;
  return (unsigned short)r;
}

static __device__ __forceinline__ void gl_lds16(const void* g, void* l) {
  __builtin_amdgcn_global_load_lds(
      (const __attribute__((address_space(1))) unsigned int*)g,
      (__attribute__((address_space(3))) unsigned int*)l, 16, 0, 0);
}

#define WAITV8 asm volatile("s_waitcnt vmcnt(8)" ::: "memory")
#define WAITV4 asm volatile("s_waitcnt vmcnt(4)" ::: "memory")
#define WAITV0 asm volatile("s_waitcnt vmcnt(0)" ::: "memory")
#define CFENCE asm volatile("" ::: "memory")

// ---------------------------------------------------------------- converts
__global__ __launch_bounds__(256) void convert_bf16(
    const float* __restrict__ in, unsigned short* __restrict__ out, int n8) {
  int i = blockIdx.x * 256 + threadIdx.x;
  if (i >= n8) return;
  const float4* p = reinterpret_cast<const float4*>(in) + (size_t)i * 2;
  float4 a = p[0], b = p[1];
  bf16x8 o;
  o[0] = f2b(a.x); o[1] = f2b(a.y); o[2] = f2b(a.z); o[3] = f2b(a.w);
  o[4] = f2b(b.x); o[5] = f2b(b.y); o[6] = f2b(b.z); o[7] = f2b(b.w);
  reinterpret_cast<bf16x8*>(out)[i] = o;
}

__global__ __launch_bounds__(256) void transpose_convert(
    const float* __restrict__ w, unsigned short* __restrict__ wt, int K, int N) {
  int idx = blockIdx.x * 256 + threadIdx.x;
  int n  = idx % N;
  int k0 = (idx / N) * 8;
  if (k0 >= K) return;
  bf16x8 o;
#pragma unroll
  for (int j = 0; j < 8; ++j) o[j] = f2b(w[(size_t)(k0 + j) * N + n]);
  *reinterpret_cast<bf16x8*>(&wt[(size_t)n * K + k0]) = o;
}

// ---------------------------------------------------------------- GEMM
// 256x256 tile, 8 waves (2M x 4N, wave tile 128x64), BK=32, 4-slot LDS ring
// (4 x 32KB = 128KB). Stage runs 3 K-steps ahead via global_load_lds;
// counted s_waitcnt vmcnt(8) retires exactly the slot being entered (never
// drains the pipeline); ONE s_barrier per K-step.
// Hazards: slot (t+3)&3 is written only after the top barrier of iter t+1,
// by which time every wave's slot reads (iter t) fed its MFMAs; in-flight
// writes never alias slots read during their window; vmcnt(8)+barrier makes
// per-wave completion mutual. Tail: vmcnt(4)/vmcnt(0) at t=30/31.
// Swizzle: col XOR ((row>>1)&3)<<4 on BOTH source and read (rule 21);
// staging LDS dest is exactly uniform + lane*16.
__global__ __launch_bounds__(512, 2) void gemm256(
    const unsigned short* __restrict__ A,
    const unsigned short* __restrict__ Bt,
    const float* __restrict__ bias, int mode,
    unsigned short* __restrict__ qb, unsigned short* __restrict__ kb,
    unsigned short* __restrict__ vt, float* __restrict__ outf) {
  __shared__ __align__(16) unsigned short lA[4][256 * 32];
  __shared__ __align__(16) unsigned short lB[4][256 * 32];
  const int t = threadIdx.x;
  const int bn = blockIdx.x, bm = blockIdx.y;
  const int w = t >> 6, lane = t & 63;
  const int lr = lane & 15, lg = lane >> 4;
  const int wm = (w >> 2) * 128, wn = (w & 3) * 64;
  const int srow = t >> 2;            // 0..127, +128 on second issue
  const int sbc  = (t & 3) * 16;      // byte col within 64B row

  f32x4 acc[8][4];
#pragma unroll
  for (int i = 0; i < 8; ++i)
#pragma unroll
    for (int j = 0; j < 4; ++j) acc[i][j] = f32x4{0.f, 0.f, 0.f, 0.f};

  const size_t am = (size_t)bm * 256, bnr = (size_t)bn * 256;

  auto stage = [&](int slot, int ks) {
    const int k0 = ks * 32;
#pragma unroll
    for (int i = 0; i < 2; ++i) {
      int row = i * 128 + srow;
      int sc = sbc ^ (((row >> 1) & 3) << 4);
      gl_lds16((const char*)(A + (am + row) * 1024 + k0) + sc,
               (char*)&lA[slot][0] + row * 64 + sbc);
    }
#pragma unroll
    for (int i = 0; i < 2; ++i) {
      int row = i * 128 + srow;
      int sc = sbc ^ (((row >> 1) & 3) << 4);
      gl_lds16((const char*)(Bt + (bnr + row) * 1024 + k0) + sc,
               (char*)&lB[slot][0] + row * 64 + sbc);
    }
  };

  stage(0, 0); stage(1, 1); stage(2, 2);   // 12 loads in flight

  for (int ks = 0; ks < 32; ++ks) {
    const int slot = ks & 3;
    if (ks <= 29) { WAITV8; } else if (ks == 30) { WAITV4; } else { WAITV0; }
    __builtin_amdgcn_s_barrier();
    CFENCE;
    if (ks + 3 < 32) stage((ks + 3) & 3, ks + 3);

    const int cswz = (lg * 16) ^ (((lr >> 1) & 3) << 4);
    bf16x8 af[8], bfr[4];
#pragma unroll
    for (int fm = 0; fm < 8; ++fm)
      af[fm] = *reinterpret_cast<const bf16x8*>(
          (const char*)&lA[slot][0] + (wm + fm * 16 + lr) * 64 + cswz);
#pragma unroll
    for (int fn = 0; fn < 4; ++fn)
      bfr[fn] = *reinterpret_cast<const bf16x8*>(
          (const char*)&lB[slot][0] + (wn + fn * 16 + lr) * 64 + cswz);

    __builtin_amdgcn_s_setprio(1);
#pragma unroll
    for (int fm = 0; fm < 8; ++fm)
#pragma unroll
      for (int fn = 0; fn < 4; ++fn)
        acc[fm][fn] = __builtin_amdgcn_mfma_f32_16x16x32_bf16(
            af[fm], bfr[fn], acc[fm][fn], 0, 0, 0);
    __builtin_amdgcn_s_setprio(0);
  }

#pragma unroll
  for (int fm = 0; fm < 8; ++fm) {
#pragma unroll
    for (int fn = 0; fn < 4; ++fn) {
#pragma unroll
      for (int r = 0; r < 4; ++r) {
        int row = bm * 256 + wm + fm * 16 + lg * 4 + r;
        int col = bn * 256 + wn + fn * 16 + lr;
        float v = acc[fm][fn][r] + bias[col];
        if (mode == 1) {
          outf[(size_t)row * 1024 + col] = v;
        } else {
          int bb = row >> 11, l = row & 2047;
          int which = col >> 10, hn = col & 1023;
          int h = hn >> 6, d = hn & 63;
          int bh = bb * 16 + h;
          if (which == 0)
            qb[((size_t)bh * 2048 + l) * 64 + d] = f2b(v * 0.125f);
          else if (which == 1)
            kb[((size_t)bh * 2048 + l) * 64 + d] = f2b(v);
          else
            vt[((size_t)bh * 64 + d) * 2048 + l] = f2b(v);
        }
      }
    }
  }
}

// ---------------------------------------------------------------- attention
// (unchanged from R4/R5 — verified passing)
__global__ __launch_bounds__(256, 2) void attn_kernel(
    const unsigned short* __restrict__ qb, const unsigned short* __restrict__ kb,
    const unsigned short* __restrict__ vt, unsigned short* __restrict__ attnb) {
  __shared__ __align__(16) unsigned short lK[2][64 * 64];
  __shared__ __align__(16) unsigned short lV[2][64 * 64];
  __shared__ __align__(16) unsigned short pl[4][2][16][72];
  const int bh = blockIdx.y;
  const int qt = (bh < 16) ? blockIdx.x : (15 - (int)blockIdx.x);
  const int q0 = qt * 128;
  const int w = threadIdx.x >> 6, lane = threadIdx.x & 63;
  const int lr = lane & 15, lg = lane >> 4;
  const int srow = w * 8 + (lane >> 3);
  const int sbc  = (lane & 7) * 16;

  const unsigned short* Kg = kb + (size_t)bh * 2048 * 64;
  const unsigned short* Vg = vt + (size_t)bh * 64 * 2048;

  auto stage = [&](int buf, int c) {
    int kv0 = c * 64;
#pragma unroll
    for (int i = 0; i < 2; ++i) {
      int row = i * 32 + srow;
      int sc = sbc ^ ((row & 7) << 4);
      gl_lds16((const char*)(Kg + (size_t)(kv0 + row) * 64) + sc,
               (char*)&lK[buf][0] + row * 128 + sbc);
      gl_lds16((const char*)(Vg + (size_t)row * 2048 + kv0) + sc,
               (char*)&lV[buf][0] + row * 128 + sbc);
    }
  };

  bf16x8 qf[2][2];
#pragma unroll
  for (int qi = 0; qi < 2; ++qi)
#pragma unroll
    for (int kk = 0; kk < 2; ++kk)
      qf[qi][kk] = *reinterpret_cast<const bf16x8*>(
          &qb[((size_t)bh * 2048 + q0 + w * 32 + qi * 16 + lr) * 64 + kk * 32 + lg * 8]);

  f32x4 acc[2][4];
#pragma unroll
  for (int qi = 0; qi < 2; ++qi)
#pragma unroll
    for (int i = 0; i < 4; ++i) acc[qi][i] = f32x4{0.f, 0.f, 0.f, 0.f};
  float m[2] = {-1e30f, -1e30f}, rs[2] = {0.f, 0.f};

  const int nc = 2 * qt + 2;
  stage(0, 0);

  for (int c = 0; c < nc; ++c) {
    const int cur = c & 1;
    __syncthreads();
    if (c + 1 < nc) stage(cur ^ 1, c + 1);

    bf16x8 kf[2][4], vf[2][4];
#pragma unroll
    for (int kk = 0; kk < 2; ++kk)
#pragma unroll
      for (int nf = 0; nf < 4; ++nf) {
        int row = nf * 16 + lr;
        int bc = (64 * kk + lg * 16) ^ ((lr & 7) << 4);
        kf[kk][nf] = *reinterpret_cast<const bf16x8*>(
            (const char*)&lK[cur][0] + row * 128 + bc);
        vf[kk][nf] = *reinterpret_cast<const bf16x8*>(
            (const char*)&lV[cur][0] + row * 128 + bc);
      }

    f32x4 s[2][4];
#pragma unroll
    for (int qi = 0; qi < 2; ++qi)
#pragma unroll
      for (int i = 0; i < 4; ++i) s[qi][i] = f32x4{0.f, 0.f, 0.f, 0.f};
#pragma unroll
    for (int qi = 0; qi < 2; ++qi)
#pragma unroll
      for (int kk = 0; kk < 2; ++kk)
#pragma unroll
        for (int nf = 0; nf < 4; ++nf)
          s[qi][nf] = __builtin_amdgcn_mfma_f32_16x16x32_bf16(
              kf[kk][nf], qf[qi][kk], s[qi][nf], 0, 0, 0);

#pragma unroll
    for (int qi = 0; qi < 2; ++qi) {
      const int qrow = q0 + w * 32 + qi * 16 + lr;
      const bool diag = (c * 64 + 63) > (q0 + w * 32 + qi * 16);
      float ps[4][4];
      float mx = -1e30f;
      if (diag) {
#pragma unroll
        for (int nf = 0; nf < 4; ++nf)
#pragma unroll
          for (int r = 0; r < 4; ++r) {
            int key = c * 64 + nf * 16 + lg * 4 + r;
            float sv = (key <= qrow) ? s[qi][nf][r] : -1e30f;
            ps[nf][r] = sv;
            mx = fmaxf(mx, sv);
          }
      } else {
#pragma unroll
        for (int nf = 0; nf < 4; ++nf)
#pragma unroll
          for (int r = 0; r < 4; ++r) {
            ps[nf][r] = s[qi][nf][r];
            mx = fmaxf(mx, ps[nf][r]);
          }
      }
      mx = fmaxf(mx, __shfl_xor(mx, 16));
      mx = fmaxf(mx, __shfl_xor(mx, 32));
      float mn = fmaxf(m[qi], mx);
      float scl = __expf(m[qi] - mn);
      m[qi] = mn;
      float ss = 0.f;
#pragma unroll
      for (int nf = 0; nf < 4; ++nf)
#pragma unroll
        for (int r = 0; r < 4; ++r) {
          float pe = __expf(ps[nf][r] - mn);
          ps[nf][r] = pe;
          ss += pe;
        }
      ss += __shfl_xor(ss, 16);
      ss += __shfl_xor(ss, 32);
      rs[qi] = rs[qi] * scl + ss;
#pragma unroll
      for (int df = 0; df < 4; ++df) acc[qi][df] *= scl;
#pragma unroll
      for (int nf = 0; nf < 4; ++nf) {
        ushort4 pk;
        pk.x = f2b(ps[nf][0]); pk.y = f2b(ps[nf][1]);
        pk.z = f2b(ps[nf][2]); pk.w = f2b(ps[nf][3]);
        *reinterpret_cast<ushort4*>(&pl[w][qi][lr][nf * 16 + lg * 4]) = pk;
      }
    }

#pragma unroll
    for (int qi = 0; qi < 2; ++qi)
#pragma unroll
      for (int kk = 0; kk < 2; ++kk) {
        bf16x8 pf = *reinterpret_cast<const bf16x8*>(&pl[w][qi][lr][kk * 32 + lg * 8]);
#pragma unroll
        for (int df = 0; df < 4; ++df)
          acc[qi][df] = __builtin_amdgcn_mfma_f32_16x16x32_bf16(
              vf[kk][df], pf, acc[qi][df], 0, 0, 0);
      }
  }

  const int b = bh >> 4, h = bh & 15;
#pragma unroll
  for (int qi = 0; qi < 2; ++qi) {
    float inv = 1.f / rs[qi];
    int qrow = q0 + w * 32 + qi * 16 + lr;
#pragma unroll
    for (int df = 0; df < 4; ++df) {
      ushort4 ov;
      ov.x = f2b(acc[qi][df][0] * inv); ov.y = f2b(acc[qi][df][1] * inv);
      ov.z = f2b(acc[qi][df][2] * inv); ov.w = f2b(acc[qi][df][3] * inv);
      *reinterpret_cast<ushort4*>(
          &attnb[((size_t)b * 2048 + qrow) * 1024 + h * 64 + df * 16 + lg * 4]) = ov;
    }
  }
}

// ---------------------------------------------------------------- launch
extern "C" void kernel_launch(void* const* d_in, const int* in_sizes, int n_in,
                              void* d_out, int out_size, void* d_ws, size_t ws_size,
                              hipStream_t stream) {
  const float* x     = (const float*)d_in[0];
  const float* w_qkv = (const float*)d_in[1];
  const float* b_qkv = (const float*)d_in[2];
  const float* w_out = (const float*)d_in[3];
  const float* b_out = (const float*)d_in[4];
  float* out = (float*)d_out;
  char* ws = (char*)d_ws;

  unsigned short* xb    = (unsigned short*)(ws);               //  8.0 MB
  unsigned short* wqkvt = (unsigned short*)(ws + 8388608);     //  6.0 MB
  unsigned short* woutt = (unsigned short*)(ws + 14680064);    //  2.0 MB
  unsigned short* qb    = (unsigned short*)(ws + 16777216);    //  8.0 MB
  unsigned short* kb    = (unsigned short*)(ws + 25165824);    //  8.0 MB
  unsigned short* vt    = (unsigned short*)(ws + 33554432);    //  8.0 MB
  unsigned short* attnb = (unsigned short*)(ws + 41943040);    //  8.0 MB

  convert_bf16<<<2048, 256, 0, stream>>>(x, xb, 4194304 / 8);
  transpose_convert<<<1536, 256, 0, stream>>>(w_qkv, wqkvt, 1024, 3072);
  transpose_convert<<<512, 256, 0, stream>>>(w_out, woutt, 1024, 1024);
  gemm256<<<dim3(12, 16), 512, 0, stream>>>(xb, wqkvt, b_qkv, 0, qb, kb, vt, nullptr);
  attn_kernel<<<dim3(16, 32), 256, 0, stream>>>(qb, kb, vt, attnb);
  gemm256<<<dim3(4, 16), 512, 0, stream>>>(attnb, woutt, b_out, 1,
                                           nullptr, nullptr, nullptr, out);
}

// Round 7
// 159.013 us; speedup vs baseline: 1.1973x; 1.1973x over previous
//
#include <hip/hip_runtime.h>
#include <hip/hip_bf16.h>

// CausalAttention MI355X: B=2 L=2048 D=1024 H=16 HD=64
// convert -> QKV GEMM (m97-structure, WAVE-UNIFORM global_load_lds dest) ->
// transpose_v -> flash attention (LDS K/V, swapped-operand) -> out GEMM.

using bf16x8 = __attribute__((ext_vector_type(8))) short;
using f32x4  = __attribute__((ext_vector_type(4))) float;

static __device__ __forceinline__ unsigned short f2b(float f) {
  unsigned u = __builtin_bit_cast(unsigned, f);
  unsigned r = (u + 0x7fffu + ((u >> 16) & 1u)) >> 16;
  return (unsigned short)r;
}

// async global->LDS, 16B/lane. lds_ptr MUST be wave-uniform (HW adds lane*16);
// per-lane variation goes on the GLOBAL address only (guide §5 caveat, m173).
static __device__ __forceinline__ void gl_lds16(const void* g, void* l) {
  __builtin_amdgcn_global_load_lds(
      (const __attribute__((address_space(1))) unsigned int*)g,
      (__attribute__((address_space(3))) unsigned int*)l, 16, 0, 0);
}

// ---------------------------------------------------------------- converts
__global__ __launch_bounds__(256) void convert_bf16(
    const float* __restrict__ in, unsigned short* __restrict__ out, int n8) {
  int i = blockIdx.x * 256 + threadIdx.x;
  if (i >= n8) return;
  const float4* p = reinterpret_cast<const float4*>(in) + (size_t)i * 2;
  float4 a = p[0], b = p[1];
  bf16x8 o;
  o[0] = f2b(a.x); o[1] = f2b(a.y); o[2] = f2b(a.z); o[3] = f2b(a.w);
  o[4] = f2b(b.x); o[5] = f2b(b.y); o[6] = f2b(b.z); o[7] = f2b(b.w);
  reinterpret_cast<bf16x8*>(out)[i] = o;
}

__global__ __launch_bounds__(256) void transpose_convert(
    const float* __restrict__ w, unsigned short* __restrict__ wt, int K, int N) {
  int idx = blockIdx.x * 256 + threadIdx.x;
  int n  = idx % N;
  int k0 = (idx / N) * 8;
  if (k0 >= K) return;
  bf16x8 o;
#pragma unroll
  for (int j = 0; j < 8; ++j) o[j] = f2b(w[(size_t)(k0 + j) * N + n]);
  *reinterpret_cast<bf16x8*>(&wt[(size_t)n * K + k0]) = o;
}

// V [bh][l][64] bf16 -> V^T [bh][64][2048] via LDS tile (both sides coalesced)
__global__ __launch_bounds__(256) void transpose_v(
    const unsigned short* __restrict__ vb, unsigned short* __restrict__ vt) {
  __shared__ unsigned short T[64][72];
  const int bh = blockIdx.y, l0 = blockIdx.x * 64;
  const int row = threadIdx.x >> 2;     // 0..63
  const int qc  = threadIdx.x & 3;      // 0..3
#pragma unroll
  for (int h = 0; h < 2; ++h) {
    bf16x8 v = *reinterpret_cast<const bf16x8*>(
        &vb[((size_t)bh * 2048 + l0 + row) * 64 + h * 32 + qc * 8]);
#pragma unroll
    for (int j = 0; j < 8; ++j) T[h * 32 + qc * 8 + j][row] = (unsigned short)v[j];
  }
  __syncthreads();
#pragma unroll
  for (int h = 0; h < 2; ++h) {
    bf16x8 o = *reinterpret_cast<const bf16x8*>(&T[row][h * 32 + qc * 8]);
    *reinterpret_cast<bf16x8*>(
        &vt[((size_t)bh * 64 + row) * 2048 + l0 + h * 32 + qc * 8]) = o;
  }
}

// ---------------------------------------------------------------- GEMM
// 128x128 tile, BK=64, stage->sync->compute (R4 structure, best measured).
// Staging: per issue each wave fills an 8-row strip; LDS dest is the strip
// base (wave-uniform), per-lane row+swizzle live on the GLOBAL address.
__global__ __launch_bounds__(256) void gemm128(
    const unsigned short* __restrict__ A,
    const unsigned short* __restrict__ Bt,
    const float* __restrict__ bias, int mode,
    unsigned short* __restrict__ qb, unsigned short* __restrict__ kb,
    unsigned short* __restrict__ vb, float* __restrict__ outf) {
  __shared__ __align__(16) unsigned short lA[128 * 64];
  __shared__ __align__(16) unsigned short lB[128 * 64];
  const int t = threadIdx.x;
  const int bn = blockIdx.x, bm = blockIdx.y;
  const int w = t >> 6, lane = t & 63;
  const int lr = lane & 15, lg = lane >> 4;
  const int wm = (w >> 1) * 64, wn = (w & 1) * 64;
  const int g8  = lane >> 3;                       // row within strip 0..7
  const int swz = ((lane & 7) * 16) ^ (g8 << 4);   // global-side swizzled col

  f32x4 acc[4][4];
#pragma unroll
  for (int i = 0; i < 4; ++i)
#pragma unroll
    for (int j = 0; j < 4; ++j) acc[i][j] = f32x4{0.f, 0.f, 0.f, 0.f};

  const size_t am = (size_t)bm * 128, bnr = (size_t)bn * 128;

  for (int k0 = 0; k0 < 1024; k0 += 64) {
#pragma unroll
    for (int i = 0; i < 4; ++i) {
      const int rs = i * 32 + w * 8;               // strip base row (uniform)
      gl_lds16((const char*)(A + (am + rs + g8) * 1024 + k0) + swz,
               (char*)lA + rs * 128);
      gl_lds16((const char*)(Bt + (bnr + rs + g8) * 1024 + k0) + swz,
               (char*)lB + rs * 128);
    }
    __syncthreads();
#pragma unroll
    for (int kk = 0; kk < 64; kk += 32) {
      bf16x8 af[4], bfr[4];
#pragma unroll
      for (int fm = 0; fm < 4; ++fm) {
        int row = wm + fm * 16 + lr;
        af[fm] = *reinterpret_cast<const bf16x8*>(
            (const char*)lA + row * 128 + ((2 * kk + lg * 16) ^ ((lr & 7) << 4)));
      }
#pragma unroll
      for (int fn = 0; fn < 4; ++fn) {
        int row = wn + fn * 16 + lr;
        bfr[fn] = *reinterpret_cast<const bf16x8*>(
            (const char*)lB + row * 128 + ((2 * kk + lg * 16) ^ ((lr & 7) << 4)));
      }
#pragma unroll
      for (int fm = 0; fm < 4; ++fm)
#pragma unroll
        for (int fn = 0; fn < 4; ++fn)
          acc[fm][fn] = __builtin_amdgcn_mfma_f32_16x16x32_bf16(
              af[fm], bfr[fn], acc[fm][fn], 0, 0, 0);
    }
    __syncthreads();
  }

#pragma unroll
  for (int fm = 0; fm < 4; ++fm) {
#pragma unroll
    for (int fn = 0; fn < 4; ++fn) {
#pragma unroll
      for (int r = 0; r < 4; ++r) {
        int row = bm * 128 + wm + fm * 16 + lg * 4 + r;
        int col = bn * 128 + wn + fn * 16 + lr;
        float v = acc[fm][fn][r] + bias[col];
        if (mode == 1) {
          outf[(size_t)row * 1024 + col] = v;
        } else {
          int bb = row >> 11, l = row & 2047;
          int which = col >> 10, hn = col & 1023;
          int h = hn >> 6, d = hn & 63;
          int bh = bb * 16 + h;
          if (which == 0)
            qb[((size_t)bh * 2048 + l) * 64 + d] = f2b(v * 0.125f);
          else if (which == 1)
            kb[((size_t)bh * 2048 + l) * 64 + d] = f2b(v);
          else
            vb[((size_t)bh * 2048 + l) * 64 + d] = f2b(v);  // coalesced now
        }
      }
    }
  }
}

// ---------------------------------------------------------------- attention
// Same structure as R4 (passing); staging switched to wave-uniform LDS dest.
__global__ __launch_bounds__(256, 2) void attn_kernel(
    const unsigned short* __restrict__ qb, const unsigned short* __restrict__ kb,
    const unsigned short* __restrict__ vt, unsigned short* __restrict__ attnb) {
  __shared__ __align__(16) unsigned short lK[2][64 * 64];
  __shared__ __align__(16) unsigned short lV[2][64 * 64];
  __shared__ __align__(16) unsigned short pl[4][2][16][72];
  const int bh = blockIdx.y;
  const int qt = (bh < 16) ? blockIdx.x : (15 - (int)blockIdx.x);
  const int q0 = qt * 128;
  const int w = threadIdx.x >> 6, lane = threadIdx.x & 63;
  const int lr = lane & 15, lg = lane >> 4;
  const int g8  = lane >> 3;
  const int swz = ((lane & 7) * 16) ^ (g8 << 4);

  const unsigned short* Kg = kb + (size_t)bh * 2048 * 64;
  const unsigned short* Vg = vt + (size_t)bh * 64 * 2048;

  auto stage = [&](int buf, int c) {
    int kv0 = c * 64;
#pragma unroll
    for (int i = 0; i < 2; ++i) {
      const int rs = i * 32 + w * 8;               // uniform strip base
      gl_lds16((const char*)(Kg + (size_t)(kv0 + rs + g8) * 64) + swz,
               (char*)&lK[buf][0] + rs * 128);
      gl_lds16((const char*)(Vg + (size_t)(rs + g8) * 2048 + kv0) + swz,
               (char*)&lV[buf][0] + rs * 128);
    }
  };

  bf16x8 qf[2][2];
#pragma unroll
  for (int qi = 0; qi < 2; ++qi)
#pragma unroll
    for (int kk = 0; kk < 2; ++kk)
      qf[qi][kk] = *reinterpret_cast<const bf16x8*>(
          &qb[((size_t)bh * 2048 + q0 + w * 32 + qi * 16 + lr) * 64 + kk * 32 + lg * 8]);

  f32x4 acc[2][4];
#pragma unroll
  for (int qi = 0; qi < 2; ++qi)
#pragma unroll
    for (int i = 0; i < 4; ++i) acc[qi][i] = f32x4{0.f, 0.f, 0.f, 0.f};
  float m[2] = {-1e30f, -1e30f}, rs[2] = {0.f, 0.f};

  const int nc = 2 * qt + 2;
  stage(0, 0);

  for (int c = 0; c < nc; ++c) {
    const int cur = c & 1;
    __syncthreads();
    if (c + 1 < nc) stage(cur ^ 1, c + 1);

    bf16x8 kf[2][4], vf[2][4];
#pragma unroll
    for (int kk = 0; kk < 2; ++kk)
#pragma unroll
      for (int nf = 0; nf < 4; ++nf) {
        int row = nf * 16 + lr;
        int bc = (64 * kk + lg * 16) ^ ((lr & 7) << 4);
        kf[kk][nf] = *reinterpret_cast<const bf16x8*>(
            (const char*)&lK[cur][0] + row * 128 + bc);
        vf[kk][nf] = *reinterpret_cast<const bf16x8*>(
            (const char*)&lV[cur][0] + row * 128 + bc);
      }

    f32x4 s[2][4];
#pragma unroll
    for (int qi = 0; qi < 2; ++qi)
#pragma unroll
      for (int i = 0; i < 4; ++i) s[qi][i] = f32x4{0.f, 0.f, 0.f, 0.f};
#pragma unroll
    for (int qi = 0; qi < 2; ++qi)
#pragma unroll
      for (int kk = 0; kk < 2; ++kk)
#pragma unroll
        for (int nf = 0; nf < 4; ++nf)
          s[qi][nf] = __builtin_amdgcn_mfma_f32_16x16x32_bf16(
              kf[kk][nf], qf[qi][kk], s[qi][nf], 0, 0, 0);

#pragma unroll
    for (int qi = 0; qi < 2; ++qi) {
      const int qrow = q0 + w * 32 + qi * 16 + lr;
      const bool diag = (c * 64 + 63) > (q0 + w * 32 + qi * 16);
      float ps[4][4];
      float mx = -1e30f;
      if (diag) {
#pragma unroll
        for (int nf = 0; nf < 4; ++nf)
#pragma unroll
          for (int r = 0; r < 4; ++r) {
            int key = c * 64 + nf * 16 + lg * 4 + r;
            float sv = (key <= qrow) ? s[qi][nf][r] : -1e30f;
            ps[nf][r] = sv;
            mx = fmaxf(mx, sv);
          }
      } else {
#pragma unroll
        for (int nf = 0; nf < 4; ++nf)
#pragma unroll
          for (int r = 0; r < 4; ++r) {
            ps[nf][r] = s[qi][nf][r];
            mx = fmaxf(mx, ps[nf][r]);
          }
      }
      mx = fmaxf(mx, __shfl_xor(mx, 16));
      mx = fmaxf(mx, __shfl_xor(mx, 32));
      float mn = fmaxf(m[qi], mx);
      float scl = __expf(m[qi] - mn);
      m[qi] = mn;
      float ss = 0.f;
#pragma unroll
      for (int nf = 0; nf < 4; ++nf)
#pragma unroll
        for (int r = 0; r < 4; ++r) {
          float pe = __expf(ps[nf][r] - mn);
          ps[nf][r] = pe;
          ss += pe;
        }
      ss += __shfl_xor(ss, 16);
      ss += __shfl_xor(ss, 32);
      rs[qi] = rs[qi] * scl + ss;
#pragma unroll
      for (int df = 0; df < 4; ++df) acc[qi][df] *= scl;
#pragma unroll
      for (int nf = 0; nf < 4; ++nf) {
        ushort4 pk;
        pk.x = f2b(ps[nf][0]); pk.y = f2b(ps[nf][1]);
        pk.z = f2b(ps[nf][2]); pk.w = f2b(ps[nf][3]);
        *reinterpret_cast<ushort4*>(&pl[w][qi][lr][nf * 16 + lg * 4]) = pk;
      }
    }

#pragma unroll
    for (int qi = 0; qi < 2; ++qi)
#pragma unroll
      for (int kk = 0; kk < 2; ++kk) {
        bf16x8 pf = *reinterpret_cast<const bf16x8*>(&pl[w][qi][lr][kk * 32 + lg * 8]);
#pragma unroll
        for (int df = 0; df < 4; ++df)
          acc[qi][df] = __builtin_amdgcn_mfma_f32_16x16x32_bf16(
              vf[kk][df], pf, acc[qi][df], 0, 0, 0);
      }
  }

  const int b = bh >> 4, h = bh & 15;
#pragma unroll
  for (int qi = 0; qi < 2; ++qi) {
    float inv = 1.f / rs[qi];
    int qrow = q0 + w * 32 + qi * 16 + lr;
#pragma unroll
    for (int df = 0; df < 4; ++df) {
      ushort4 ov;
      ov.x = f2b(acc[qi][df][0] * inv); ov.y = f2b(acc[qi][df][1] * inv);
      ov.z = f2b(acc[qi][df][2] * inv); ov.w = f2b(acc[qi][df][3] * inv);
      *reinterpret_cast<ushort4*>(
          &attnb[((size_t)b * 2048 + qrow) * 1024 + h * 64 + df * 16 + lg * 4]) = ov;
    }
  }
}

// ---------------------------------------------------------------- launch
extern "C" void kernel_launch(void* const* d_in, const int* in_sizes, int n_in,
                              void* d_out, int out_size, void* d_ws, size_t ws_size,
                              hipStream_t stream) {
  const float* x     = (const float*)d_in[0];
  const float* w_qkv = (const float*)d_in[1];
  const float* b_qkv = (const float*)d_in[2];
  const float* w_out = (const float*)d_in[3];
  const float* b_out = (const float*)d_in[4];
  float* out = (float*)d_out;
  char* ws = (char*)d_ws;

  // vt reuses the xb region (xb dead after QKV GEMM; transpose_v runs after).
  unsigned short* xb    = (unsigned short*)(ws);               //  8.0 MB (-> vt)
  unsigned short* vt    = (unsigned short*)(ws);
  unsigned short* wqkvt = (unsigned short*)(ws + 8388608);     //  6.0 MB
  unsigned short* woutt = (unsigned short*)(ws + 14680064);    //  2.0 MB
  unsigned short* qb    = (unsigned short*)(ws + 16777216);    //  8.0 MB
  unsigned short* kb    = (unsigned short*)(ws + 25165824);    //  8.0 MB
  unsigned short* vb    = (unsigned short*)(ws + 33554432);    //  8.0 MB
  unsigned short* attnb = (unsigned short*)(ws + 41943040);    //  8.0 MB

  convert_bf16<<<2048, 256, 0, stream>>>(x, xb, 4194304 / 8);
  transpose_convert<<<1536, 256, 0, stream>>>(w_qkv, wqkvt, 1024, 3072);
  transpose_convert<<<512, 256, 0, stream>>>(w_out, woutt, 1024, 1024);
  gemm128<<<dim3(24, 32), 256, 0, stream>>>(xb, wqkvt, b_qkv, 0, qb, kb, vb, nullptr);
  transpose_v<<<dim3(32, 32), 256, 0, stream>>>(vb, vt);
  attn_kernel<<<dim3(16, 32), 256, 0, stream>>>(qb, kb, vt, attnb);
  gemm128<<<dim3(8, 32), 256, 0, stream>>>(attnb, woutt, b_out, 1,
                                           nullptr, nullptr, nullptr, out);
}